// Round 1
// baseline (294.842 us; speedup 1.0000x reference)
//
#include <hip/hip_runtime.h>
#include <cstdint>
#include <cstddef>

#define I_DIM 4096
#define O_DIM 4096
#define RNK 32
#define NGRP 64
#define N_TOK 4096

typedef int v4i __attribute__((ext_vector_type(4)));

__device__ __forceinline__ int clamp_i8(float v) {
    int q = (int)rintf(v);           // round half to even, matches jnp.round
    q = q < -128 ? -128 : q;
    q = q > 127 ? 127 : q;
    return q;
}

// ---------------------------------------------------------------------------
// Kernel 1: dequantize W (int4 + group affine + SVD correction), compute
// per-output-column scale_w = max|W[o,:]|/127, write W_q as int8 in [O, I]
// (i.e. B^T layout for the GEMM). Two passes (max, then quantize), 8 rows
// per block so svd_down is read once per pass per block (L2-resident).
// ---------------------------------------------------------------------------
#define BO 8

__global__ __launch_bounds__(256) void quant_w_kernel(
    const int* __restrict__ w_packed, const float* __restrict__ svd_up,
    const float* __restrict__ svd_down, const float* __restrict__ scale,
    const float* __restrict__ zp, char* __restrict__ w_q,
    float* __restrict__ scale_w)
{
    __shared__ float s_up[BO][RNK];
    __shared__ float s_sc[BO][NGRP];
    __shared__ float s_zp[BO][NGRP];
    __shared__ float s_red[BO][4];
    __shared__ float s_sw[BO];

    const int tid = threadIdx.x;
    const int o0 = blockIdx.x * BO;

    // stage svd_up rows (8x32 = 256 floats) and group scale/zp (8x64)
    s_up[tid >> 5][tid & 31] = svd_up[(size_t)(o0 + (tid >> 5)) * RNK + (tid & 31)];
    for (int t = tid; t < BO * NGRP; t += 256) {
        s_sc[t >> 6][t & 63] = scale[(size_t)(o0 + (t >> 6)) * NGRP + (t & 63)];
        s_zp[t >> 6][t & 63] = zp[(size_t)(o0 + (t >> 6)) * NGRP + (t & 63)];
    }
    __syncthreads();

    float vmax[BO];
#pragma unroll
    for (int ro = 0; ro < BO; ro++) vmax[ro] = 0.0f;

    // ---- pass 1: compute W, track per-row max |W| ----
    for (int j = 0; j < 8; j++) {
        const int p = tid + 256 * j;   // byte-pair index within a row (0..2047)
        const int i = 2 * p;           // column index (even)
        const int g = i >> 6;          // group (GS=64; i and i+1 same group)
        float c0[BO], c1[BO];
#pragma unroll
        for (int ro = 0; ro < BO; ro++) { c0[ro] = 0.0f; c1[ro] = 0.0f; }
#pragma unroll 4
        for (int r = 0; r < RNK; r++) {
            const float2 d = *(const float2*)&svd_down[(size_t)r * I_DIM + i];
#pragma unroll
            for (int ro = 0; ro < BO; ro++) {
                c0[ro] += s_up[ro][r] * d.x;
                c1[ro] += s_up[ro][r] * d.y;
            }
        }
#pragma unroll
        for (int ro = 0; ro < BO; ro++) {
            const int b = w_packed[(size_t)(o0 + ro) * (I_DIM / 2) + p];
            const float sc = s_sc[ro][g], z = s_zp[ro][g];
            const float w0 = ((float)(b & 0xF) - z) * sc + c0[ro];
            const float w1 = ((float)((b >> 4) & 0xF) - z) * sc + c1[ro];
            vmax[ro] = fmaxf(vmax[ro], fmaxf(fabsf(w0), fabsf(w1)));
        }
    }

    // block-wide max reduction per row
    const int lane = tid & 63, wv = tid >> 6;
#pragma unroll
    for (int ro = 0; ro < BO; ro++) {
        float m = vmax[ro];
        for (int off = 32; off > 0; off >>= 1)
            m = fmaxf(m, __shfl_down(m, off, 64));
        if (lane == 0) s_red[ro][wv] = m;
    }
    __syncthreads();
    if (tid < BO) {
        const float m = fmaxf(fmaxf(s_red[tid][0], s_red[tid][1]),
                              fmaxf(s_red[tid][2], s_red[tid][3]));
        const float sw = m / 127.0f;
        scale_w[o0 + tid] = sw;
        s_sw[tid] = sw;
    }
    __syncthreads();

    // ---- pass 2: recompute W, quantize, write W_q (B^T layout, int8) ----
    for (int j = 0; j < 8; j++) {
        const int p = tid + 256 * j;
        const int i = 2 * p;
        const int g = i >> 6;
        float c0[BO], c1[BO];
#pragma unroll
        for (int ro = 0; ro < BO; ro++) { c0[ro] = 0.0f; c1[ro] = 0.0f; }
#pragma unroll 4
        for (int r = 0; r < RNK; r++) {
            const float2 d = *(const float2*)&svd_down[(size_t)r * I_DIM + i];
#pragma unroll
            for (int ro = 0; ro < BO; ro++) {
                c0[ro] += s_up[ro][r] * d.x;
                c1[ro] += s_up[ro][r] * d.y;
            }
        }
#pragma unroll
        for (int ro = 0; ro < BO; ro++) {
            const int b = w_packed[(size_t)(o0 + ro) * (I_DIM / 2) + p];
            const float sc = s_sc[ro][g], z = s_zp[ro][g];
            const float w0 = ((float)(b & 0xF) - z) * sc + c0[ro];
            const float w1 = ((float)((b >> 4) & 0xF) - z) * sc + c1[ro];
            const float sw = s_sw[ro];
            const int q0 = clamp_i8(w0 / sw);
            const int q1 = clamp_i8(w1 / sw);
            ((short*)w_q)[(size_t)(o0 + ro) * (I_DIM / 2) + p] =
                (short)((q0 & 0xFF) | ((q1 & 0xFF) << 8));
        }
    }
}

// ---------------------------------------------------------------------------
// Kernel 2: per-token dynamic activation quant. One block per row.
// ---------------------------------------------------------------------------
__global__ __launch_bounds__(256) void quant_x_kernel(
    const float* __restrict__ x, char* __restrict__ x_q,
    float* __restrict__ scale_x)
{
    const int n = blockIdx.x;
    const int tid = threadIdx.x;
    const float4* xr = (const float4*)(x + (size_t)n * I_DIM);
    float4 v[4];
    float m = 0.0f;
#pragma unroll
    for (int j = 0; j < 4; j++) {
        v[j] = xr[tid + 256 * j];
        m = fmaxf(m, fmaxf(fmaxf(fabsf(v[j].x), fabsf(v[j].y)),
                           fmaxf(fabsf(v[j].z), fabsf(v[j].w))));
    }
    __shared__ float s_red[4];
    __shared__ float s_sx;
    for (int off = 32; off > 0; off >>= 1)
        m = fmaxf(m, __shfl_down(m, off, 64));
    if ((tid & 63) == 0) s_red[tid >> 6] = m;
    __syncthreads();
    if (tid == 0) {
        const float mm = fmaxf(fmaxf(s_red[0], s_red[1]),
                               fmaxf(s_red[2], s_red[3]));
        const float sx = mm / 127.0f;
        scale_x[n] = sx;
        s_sx = sx;
    }
    __syncthreads();
    const float sx = s_sx;
    int* outw = (int*)(x_q + (size_t)n * I_DIM);
#pragma unroll
    for (int j = 0; j < 4; j++) {
        const int q0 = clamp_i8(v[j].x / sx);
        const int q1 = clamp_i8(v[j].y / sx);
        const int q2 = clamp_i8(v[j].z / sx);
        const int q3 = clamp_i8(v[j].w / sx);
        outw[tid + 256 * j] =
            (q0 & 0xFF) | ((q1 & 0xFF) << 8) | ((q2 & 0xFF) << 16) | ((q3 & 0xFF) << 24);
    }
}

// ---------------------------------------------------------------------------
// Kernel 3: int8 GEMM (m97 structure). C[n,o] = sum_k x_q[n,k]*W_q^T[o,k].
// 128x128 tile / block, BK=128 bytes, 4 waves each computing 4x4 16x16 tiles
// with mfma_i32_16x16x64_i8. global_load_lds width-16 staging; XOR-swizzled
// K-chunks to keep ds_read_b128 at 2-way bank aliasing (free).
// ---------------------------------------------------------------------------
#define BM 128
#define BN 128
#define BK 128

__global__ __launch_bounds__(256) void gemm_i8_kernel(
    const char* __restrict__ x_q, const char* __restrict__ w_q,
    const float* __restrict__ scale_x, const float* __restrict__ scale_w,
    const float* __restrict__ bias, float* __restrict__ out)
{
    __shared__ v4i As4[BM * BK / 16];
    __shared__ v4i Bs4[BN * BK / 16];
    char* As = (char*)As4;
    char* Bs = (char*)Bs4;

    const int tid = threadIdx.x;
    const int bm0 = blockIdx.x * BM;
    const int bn0 = blockIdx.y * BN;
    const int lane = tid & 63, wv = tid >> 6;
    const int wm = wv & 1, wn = wv >> 1;
    const int quad = lane >> 4, l15 = lane & 15;

    v4i acc[4][4];
#pragma unroll
    for (int mt = 0; mt < 4; mt++)
#pragma unroll
        for (int nt = 0; nt < 4; nt++)
            acc[mt][nt] = (v4i){0, 0, 0, 0};

    for (int kk = 0; kk < I_DIM / BK; kk++) {
        const int k0 = kk * BK;
        // stage A (128x128B) and B^T (128x128B): 8 chunks of 16B per thread.
        // LDS slot c holds logical chunk (row=c>>3, kc=(c&7)^(row&7)).
#pragma unroll
        for (int j = 0; j < 4; j++) {
            const int c = tid + 256 * j;
            const int row = c >> 3;
            const int kc = (c & 7) ^ (row & 7);
            const char* ga = x_q + (size_t)(bm0 + row) * I_DIM + k0 + kc * 16;
            __builtin_amdgcn_global_load_lds(
                (const __attribute__((address_space(1))) unsigned int*)ga,
                (__attribute__((address_space(3))) unsigned int*)(As + c * 16),
                16, 0, 0);
            const char* gb = w_q + (size_t)(bn0 + row) * I_DIM + k0 + kc * 16;
            __builtin_amdgcn_global_load_lds(
                (const __attribute__((address_space(1))) unsigned int*)gb,
                (__attribute__((address_space(3))) unsigned int*)(Bs + c * 16),
                16, 0, 0);
        }
        __syncthreads();
#pragma unroll
        for (int s = 0; s < 2; s++) {
            v4i af[4], bf[4];
#pragma unroll
            for (int mt = 0; mt < 4; mt++) {
                const int row = wm * 64 + mt * 16 + l15;
                const int kc = (s * 4 + quad) ^ (l15 & 7);
                af[mt] = *(const v4i*)(As + row * BK + kc * 16);
            }
#pragma unroll
            for (int nt = 0; nt < 4; nt++) {
                const int row = wn * 64 + nt * 16 + l15;
                const int kc = (s * 4 + quad) ^ (l15 & 7);
                bf[nt] = *(const v4i*)(Bs + row * BK + kc * 16);
            }
#pragma unroll
            for (int mt = 0; mt < 4; mt++)
#pragma unroll
                for (int nt = 0; nt < 4; nt++)
                    acc[mt][nt] = __builtin_amdgcn_mfma_i32_16x16x64_i8(
                        af[mt], bf[nt], acc[mt][nt], 0, 0, 0);
        }
        __syncthreads();
    }

    // epilogue: C/D layout col = lane&15, row = quad*4 + reg
#pragma unroll
    for (int mt = 0; mt < 4; mt++) {
        const int n0 = bm0 + wm * 64 + mt * 16 + quad * 4;
        float sx[4];
#pragma unroll
        for (int r = 0; r < 4; r++) sx[r] = scale_x[n0 + r];
#pragma unroll
        for (int nt = 0; nt < 4; nt++) {
            const int oc = bn0 + wn * 64 + nt * 16 + l15;
            const float sw = scale_w[oc];
            const float bs = bias[oc];
#pragma unroll
            for (int r = 0; r < 4; r++) {
                out[(size_t)(n0 + r) * O_DIM + oc] =
                    (float)acc[mt][nt][r] * sx[r] * sw + bs;
            }
        }
    }
}

// ---------------------------------------------------------------------------
extern "C" void kernel_launch(void* const* d_in, const int* in_sizes, int n_in,
                              void* d_out, int out_size, void* d_ws, size_t ws_size,
                              hipStream_t stream) {
    const float* x        = (const float*)d_in[0];
    const int*   w_packed = (const int*)d_in[1];
    const float* svd_up   = (const float*)d_in[2];
    const float* svd_down = (const float*)d_in[3];
    const float* scale    = (const float*)d_in[4];
    const float* zp       = (const float*)d_in[5];
    const float* bias     = (const float*)d_in[6];
    float* out = (float*)d_out;

    char* ws = (char*)d_ws;
    char*  w_q     = ws;                                   // 16 MB int8 [O, I]
    char*  x_q     = ws + ((size_t)16 << 20);              // 16 MB int8 [N, I]
    float* scale_w = (float*)(ws + ((size_t)32 << 20));    // 16 KB
    float* scale_x = (float*)(ws + ((size_t)32 << 20) + 16384);  // 16 KB

    quant_w_kernel<<<O_DIM / BO, 256, 0, stream>>>(w_packed, svd_up, svd_down,
                                                   scale, zp, w_q, scale_w);
    quant_x_kernel<<<N_TOK, 256, 0, stream>>>(x, x_q, scale_x);
    gemm_i8_kernel<<<dim3(N_TOK / BM, O_DIM / BN), 256, 0, stream>>>(
        x_q, w_q, scale_x, scale_w, bias, out);
}

// Round 2
// 254.717 us; speedup vs baseline: 1.1575x; 1.1575x over previous
//
#include <hip/hip_runtime.h>
#include <cstdint>
#include <cstddef>

#define I_DIM 4096
#define O_DIM 4096
#define RNK 32
#define NGRP 64
#define N_TOK 4096

typedef int v4i __attribute__((ext_vector_type(4)));

__device__ __forceinline__ int clamp_i8(float v) {
    int q = (int)rintf(v);           // round half to even, matches jnp.round
    q = q < -128 ? -128 : q;
    q = q > 127 ? 127 : q;
    return q;
}

// ---------------------------------------------------------------------------
// Kernel 1: dequantize W (int4 + group affine + SVD correction), compute
// per-output-row scale_w = max|W[o,:]|/127, write W_q int8 in [O, I].
// Single pass: BO=4 rows/block, each thread holds its 64 W values in VGPRs
// (4 col-quads x 4 rows x 4 cols). svd_up read via block-uniform global
// loads -> s_load/SGPR (no LDS traffic in the FMA loop).
// ---------------------------------------------------------------------------
#define BO 4

__global__ __launch_bounds__(256, 4) void quant_w_kernel(
    const int* __restrict__ w_packed, const float* __restrict__ svd_up,
    const float* __restrict__ svd_down, const float* __restrict__ scale,
    const float* __restrict__ zp, char* __restrict__ w_q,
    float* __restrict__ scale_w)
{
    __shared__ float s_sc[BO][NGRP];
    __shared__ float s_zp[BO][NGRP];
    __shared__ float s_red[BO][4];
    __shared__ float s_sw[BO];

    const int tid = threadIdx.x;
    const int o0 = blockIdx.x * BO;

    for (int t = tid; t < BO * NGRP; t += 256) {
        s_sc[t >> 6][t & 63] = scale[(size_t)(o0 + (t >> 6)) * NGRP + (t & 63)];
        s_zp[t >> 6][t & 63] = zp[(size_t)(o0 + (t >> 6)) * NGRP + (t & 63)];
    }
    __syncthreads();

    float W[4][BO][4];     // [col-quad jq][row ro][col-in-quad]
    float vmax[BO];
#pragma unroll
    for (int ro = 0; ro < BO; ro++) vmax[ro] = 0.0f;

#pragma unroll
    for (int jq = 0; jq < 4; jq++) {
        const int q = tid + 256 * jq;    // col-quad index, 0..1023
        const int i = 4 * q;             // first column of the quad
        const int g = q >> 4;            // group (4 cols always same group)

        // init with affine dequant of the 4 int4 values
#pragma unroll
        for (int ro = 0; ro < BO; ro++) {
            const int2 b2 = *(const int2*)&w_packed[(size_t)(o0 + ro) * (I_DIM / 2) + 2 * q];
            const float sc = s_sc[ro][g], z = s_zp[ro][g];
            W[jq][ro][0] = ((float)(b2.x & 0xF) - z) * sc;
            W[jq][ro][1] = ((float)((b2.x >> 4) & 0xF) - z) * sc;
            W[jq][ro][2] = ((float)(b2.y & 0xF) - z) * sc;
            W[jq][ro][3] = ((float)((b2.y >> 4) & 0xF) - z) * sc;
        }

        // rank-32 SVD correction; svd_up loads are block-uniform -> SGPR
#pragma unroll 4
        for (int r = 0; r < RNK; r++) {
            const float4 d = *(const float4*)&svd_down[(size_t)r * I_DIM + i];
#pragma unroll
            for (int ro = 0; ro < BO; ro++) {
                const float u = svd_up[(size_t)(o0 + ro) * RNK + r];
                W[jq][ro][0] += u * d.x;
                W[jq][ro][1] += u * d.y;
                W[jq][ro][2] += u * d.z;
                W[jq][ro][3] += u * d.w;
            }
        }

#pragma unroll
        for (int ro = 0; ro < BO; ro++) {
            vmax[ro] = fmaxf(vmax[ro],
                fmaxf(fmaxf(fabsf(W[jq][ro][0]), fabsf(W[jq][ro][1])),
                      fmaxf(fabsf(W[jq][ro][2]), fabsf(W[jq][ro][3]))));
        }
    }

    // block-wide max per row
    const int lane = tid & 63, wv = tid >> 6;
#pragma unroll
    for (int ro = 0; ro < BO; ro++) {
        float m = vmax[ro];
        for (int off = 32; off > 0; off >>= 1)
            m = fmaxf(m, __shfl_down(m, off, 64));
        if (lane == 0) s_red[ro][wv] = m;
    }
    __syncthreads();
    if (tid < BO) {
        const float m = fmaxf(fmaxf(s_red[tid][0], s_red[tid][1]),
                              fmaxf(s_red[tid][2], s_red[tid][3]));
        const float sw = m / 127.0f;
        scale_w[o0 + tid] = sw;
        s_sw[tid] = sw;
    }
    __syncthreads();

    float inv[BO];
#pragma unroll
    for (int ro = 0; ro < BO; ro++) inv[ro] = 1.0f / s_sw[ro];

    // quantize from registers, pack 4 int8 per int store
#pragma unroll
    for (int jq = 0; jq < 4; jq++) {
        const int q = tid + 256 * jq;
#pragma unroll
        for (int ro = 0; ro < BO; ro++) {
            const int q0 = clamp_i8(W[jq][ro][0] * inv[ro]);
            const int q1 = clamp_i8(W[jq][ro][1] * inv[ro]);
            const int q2 = clamp_i8(W[jq][ro][2] * inv[ro]);
            const int q3 = clamp_i8(W[jq][ro][3] * inv[ro]);
            ((int*)w_q)[(size_t)(o0 + ro) * (I_DIM / 4) + q] =
                (q0 & 0xFF) | ((q1 & 0xFF) << 8) | ((q2 & 0xFF) << 16) | ((q3 & 0xFF) << 24);
        }
    }
}

// ---------------------------------------------------------------------------
// Kernel 2: per-token dynamic activation quant. One block per row.
// ---------------------------------------------------------------------------
__global__ __launch_bounds__(256) void quant_x_kernel(
    const float* __restrict__ x, char* __restrict__ x_q,
    float* __restrict__ scale_x)
{
    const int n = blockIdx.x;
    const int tid = threadIdx.x;
    const float4* xr = (const float4*)(x + (size_t)n * I_DIM);
    float4 v[4];
    float m = 0.0f;
#pragma unroll
    for (int j = 0; j < 4; j++) {
        v[j] = xr[tid + 256 * j];
        m = fmaxf(m, fmaxf(fmaxf(fabsf(v[j].x), fabsf(v[j].y)),
                           fmaxf(fabsf(v[j].z), fabsf(v[j].w))));
    }
    __shared__ float s_red[4];
    __shared__ float s_sx;
    for (int off = 32; off > 0; off >>= 1)
        m = fmaxf(m, __shfl_down(m, off, 64));
    if ((tid & 63) == 0) s_red[tid >> 6] = m;
    __syncthreads();
    if (tid == 0) {
        const float mm = fmaxf(fmaxf(s_red[0], s_red[1]),
                               fmaxf(s_red[2], s_red[3]));
        const float sx = mm / 127.0f;
        scale_x[n] = sx;
        s_sx = sx;
    }
    __syncthreads();
    const float sx = s_sx;
    int* outw = (int*)(x_q + (size_t)n * I_DIM);
#pragma unroll
    for (int j = 0; j < 4; j++) {
        const int q0 = clamp_i8(v[j].x / sx);
        const int q1 = clamp_i8(v[j].y / sx);
        const int q2 = clamp_i8(v[j].z / sx);
        const int q3 = clamp_i8(v[j].w / sx);
        outw[tid + 256 * j] =
            (q0 & 0xFF) | ((q1 & 0xFF) << 8) | ((q2 & 0xFF) << 16) | ((q3 & 0xFF) << 24);
    }
}

// ---------------------------------------------------------------------------
// Kernel 3: int8 GEMM (m97 structure). C[n,o] = sum_k x_q[n,k]*W_q^T[o,k].
// 128x128 tile / block, BK=128 bytes, 4 waves each computing 4x4 16x16 tiles
// with mfma_i32_16x16x64_i8. global_load_lds width-16 staging; XOR-swizzled
// K-chunks keep ds_read_b128 conflict-free (measured: SQ_LDS_BANK_CONFLICT=0).
// ---------------------------------------------------------------------------
#define BM 128
#define BN 128
#define BK 128

__global__ __launch_bounds__(256) void gemm_i8_kernel(
    const char* __restrict__ x_q, const char* __restrict__ w_q,
    const float* __restrict__ scale_x, const float* __restrict__ scale_w,
    const float* __restrict__ bias, float* __restrict__ out)
{
    __shared__ v4i As4[BM * BK / 16];
    __shared__ v4i Bs4[BN * BK / 16];
    char* As = (char*)As4;
    char* Bs = (char*)Bs4;

    const int tid = threadIdx.x;
    const int bm0 = blockIdx.x * BM;
    const int bn0 = blockIdx.y * BN;
    const int lane = tid & 63, wv = tid >> 6;
    const int wm = wv & 1, wn = wv >> 1;
    const int quad = lane >> 4, l15 = lane & 15;

    v4i acc[4][4];
#pragma unroll
    for (int mt = 0; mt < 4; mt++)
#pragma unroll
        for (int nt = 0; nt < 4; nt++)
            acc[mt][nt] = (v4i){0, 0, 0, 0};

    for (int kk = 0; kk < I_DIM / BK; kk++) {
        const int k0 = kk * BK;
#pragma unroll
        for (int j = 0; j < 4; j++) {
            const int c = tid + 256 * j;
            const int row = c >> 3;
            const int kc = (c & 7) ^ (row & 7);
            const char* ga = x_q + (size_t)(bm0 + row) * I_DIM + k0 + kc * 16;
            __builtin_amdgcn_global_load_lds(
                (const __attribute__((address_space(1))) unsigned int*)ga,
                (__attribute__((address_space(3))) unsigned int*)(As + c * 16),
                16, 0, 0);
            const char* gb = w_q + (size_t)(bn0 + row) * I_DIM + k0 + kc * 16;
            __builtin_amdgcn_global_load_lds(
                (const __attribute__((address_space(1))) unsigned int*)gb,
                (__attribute__((address_space(3))) unsigned int*)(Bs + c * 16),
                16, 0, 0);
        }
        __syncthreads();
#pragma unroll
        for (int s = 0; s < 2; s++) {
            v4i af[4], bf[4];
#pragma unroll
            for (int mt = 0; mt < 4; mt++) {
                const int row = wm * 64 + mt * 16 + l15;
                const int kc = (s * 4 + quad) ^ (l15 & 7);
                af[mt] = *(const v4i*)(As + row * BK + kc * 16);
            }
#pragma unroll
            for (int nt = 0; nt < 4; nt++) {
                const int row = wn * 64 + nt * 16 + l15;
                const int kc = (s * 4 + quad) ^ (l15 & 7);
                bf[nt] = *(const v4i*)(Bs + row * BK + kc * 16);
            }
#pragma unroll
            for (int mt = 0; mt < 4; mt++)
#pragma unroll
                for (int nt = 0; nt < 4; nt++)
                    acc[mt][nt] = __builtin_amdgcn_mfma_i32_16x16x64_i8(
                        af[mt], bf[nt], acc[mt][nt], 0, 0, 0);
        }
        __syncthreads();
    }

    // epilogue: C/D layout col = lane&15, row = quad*4 + reg
#pragma unroll
    for (int mt = 0; mt < 4; mt++) {
        const int n0 = bm0 + wm * 64 + mt * 16 + quad * 4;
        float sx[4];
#pragma unroll
        for (int r = 0; r < 4; r++) sx[r] = scale_x[n0 + r];
#pragma unroll
        for (int nt = 0; nt < 4; nt++) {
            const int oc = bn0 + wn * 64 + nt * 16 + l15;
            const float sw = scale_w[oc];
            const float bs = bias[oc];
#pragma unroll
            for (int r = 0; r < 4; r++) {
                out[(size_t)(n0 + r) * O_DIM + oc] =
                    (float)acc[mt][nt][r] * sx[r] * sw + bs;
            }
        }
    }
}

// ---------------------------------------------------------------------------
extern "C" void kernel_launch(void* const* d_in, const int* in_sizes, int n_in,
                              void* d_out, int out_size, void* d_ws, size_t ws_size,
                              hipStream_t stream) {
    const float* x        = (const float*)d_in[0];
    const int*   w_packed = (const int*)d_in[1];
    const float* svd_up   = (const float*)d_in[2];
    const float* svd_down = (const float*)d_in[3];
    const float* scale    = (const float*)d_in[4];
    const float* zp       = (const float*)d_in[5];
    const float* bias     = (const float*)d_in[6];
    float* out = (float*)d_out;

    char* ws = (char*)d_ws;
    char*  w_q     = ws;                                   // 16 MB int8 [O, I]
    char*  x_q     = ws + ((size_t)16 << 20);              // 16 MB int8 [N, I]
    float* scale_w = (float*)(ws + ((size_t)32 << 20));    // 16 KB
    float* scale_x = (float*)(ws + ((size_t)32 << 20) + 16384);  // 16 KB

    quant_w_kernel<<<O_DIM / BO, 256, 0, stream>>>(w_packed, svd_up, svd_down,
                                                   scale, zp, w_q, scale_w);
    quant_x_kernel<<<N_TOK, 256, 0, stream>>>(x, x_q, scale_x);
    gemm_i8_kernel<<<dim3(N_TOK / BM, O_DIM / BN), 256, 0, stream>>>(
        x_q, w_q, scale_x, scale_w, bias, out);
}